// Round 1
// baseline (100.587 us; speedup 1.0000x reference)
//
#include <hip/hip_runtime.h>
#include <math.h>

#define EPS 1e-8f
#define MARGIN 0.5f

// ---------------- Kernel 1: per-batch-row positive cosine + anchor norm ----
// One wave (64 lanes) per row; D = 256 -> float4 per lane.
__global__ void pos_sim_kernel(const float* __restrict__ anchor,
                               const float* __restrict__ pos,
                               float* __restrict__ pos_sim,
                               float* __restrict__ norm_a,
                               int B) {
    int wave = (blockIdx.x * blockDim.x + threadIdx.x) >> 6;
    int lane = threadIdx.x & 63;
    if (wave >= B) return;

    const float4 a = *reinterpret_cast<const float4*>(anchor + (size_t)wave * 256 + lane * 4);
    const float4 p = *reinterpret_cast<const float4*>(pos    + (size_t)wave * 256 + lane * 4);

    float dot = a.x * p.x + a.y * p.y + a.z * p.z + a.w * p.w;
    float na  = a.x * a.x + a.y * a.y + a.z * a.z + a.w * a.w;
    float nb  = p.x * p.x + p.y * p.y + p.z * p.z + p.w * p.w;

    #pragma unroll
    for (int off = 32; off > 0; off >>= 1) {
        dot += __shfl_xor(dot, off);
        na  += __shfl_xor(na,  off);
        nb  += __shfl_xor(nb,  off);
    }
    if (lane == 0) {
        float sna = sqrtf(na);
        pos_sim[wave] = dot / fmaxf(sna * sqrtf(nb), EPS);
        norm_a[wave]  = sna;
    }
}

// ---------------- Kernel 2: per-negative cosine + triplet + segment atomics -
__global__ void neg_kernel(const float* __restrict__ anchor,
                           const float* __restrict__ neg,
                           const int*  __restrict__ idx,
                           const float* __restrict__ pos_sim,
                           const float* __restrict__ norm_a,
                           float* __restrict__ sums,
                           float* __restrict__ counts,
                           int N) {
    int wave = (blockIdx.x * blockDim.x + threadIdx.x) >> 6;
    int lane = threadIdx.x & 63;
    if (wave >= N) return;

    int b = idx[wave];  // broadcast load (all lanes same address)

    const float4 a = *reinterpret_cast<const float4*>(anchor + (size_t)b * 256 + lane * 4);
    const float4 n = *reinterpret_cast<const float4*>(neg + (size_t)wave * 256 + lane * 4);

    float dot = a.x * n.x + a.y * n.y + a.z * n.z + a.w * n.w;
    float nn  = n.x * n.x + n.y * n.y + n.z * n.z + n.w * n.w;

    #pragma unroll
    for (int off = 32; off > 0; off >>= 1) {
        dot += __shfl_xor(dot, off);
        nn  += __shfl_xor(nn,  off);
    }
    if (lane == 0) {
        float sim = dot / fmaxf(norm_a[b] * sqrtf(nn), EPS);
        float t   = fmaxf(MARGIN + sim - pos_sim[b], 0.0f);
        atomicAdd(&sums[b],   t);
        atomicAdd(&counts[b], 1.0f);
    }
}

// ---------------- Kernel 3: segment means -> scalar -------------------------
__global__ void finalize_kernel(const float* __restrict__ sums,
                                const float* __restrict__ counts,
                                float* __restrict__ out, int B) {
    float local = 0.0f;
    for (int i = threadIdx.x; i < B; i += blockDim.x) {
        float c = counts[i];
        local += (c > 0.0f) ? (sums[i] / c) : 0.0f;
    }
    #pragma unroll
    for (int off = 32; off > 0; off >>= 1)
        local += __shfl_xor(local, off);

    __shared__ float ws[8];
    int wid = threadIdx.x >> 6;
    if ((threadIdx.x & 63) == 0) ws[wid] = local;
    __syncthreads();
    if (threadIdx.x == 0) {
        float tot = 0.0f;
        int nw = blockDim.x >> 6;
        for (int w = 0; w < nw; ++w) tot += ws[w];
        out[0] = tot / (float)B;
    }
}

extern "C" void kernel_launch(void* const* d_in, const int* in_sizes, int n_in,
                              void* d_out, int out_size, void* d_ws, size_t ws_size,
                              hipStream_t stream) {
    const float* anchor = (const float*)d_in[0];
    const float* pos    = (const float*)d_in[1];
    const float* neg    = (const float*)d_in[2];
    const int*   idx    = (const int*)d_in[3];

    const int D = 256;
    int B = in_sizes[0] / D;   // 4096
    int N = in_sizes[3];       // 262144

    float* pos_sim = (float*)d_ws;
    float* norm_a  = pos_sim + B;
    float* sums    = norm_a + B;
    float* counts  = sums + B;

    // zero the segment accumulators (harness poisons ws with 0xAA)
    hipMemsetAsync(sums, 0, 2 * (size_t)B * sizeof(float), stream);

    // kernel 1: B waves
    {
        int threads = 256;
        int waves_per_block = threads / 64;
        int blocks = (B + waves_per_block - 1) / waves_per_block;
        pos_sim_kernel<<<blocks, threads, 0, stream>>>(anchor, pos, pos_sim, norm_a, B);
    }

    // kernel 2: N waves
    {
        int threads = 256;
        int waves_per_block = threads / 64;
        int blocks = (N + waves_per_block - 1) / waves_per_block;
        neg_kernel<<<blocks, threads, 0, stream>>>(anchor, neg, idx, pos_sim, norm_a,
                                                   sums, counts, N);
    }

    // kernel 3: reduce to scalar
    finalize_kernel<<<1, 256, 0, stream>>>(sums, counts, (float*)d_out, B);
}

// Round 2
// 91.345 us; speedup vs baseline: 1.1012x; 1.1012x over previous
//
#include <hip/hip_runtime.h>
#include <math.h>

#define EPS 1e-8f
#define MARGIN 0.5f

// ---------------- Kernel 1: per-batch-row positive cosine + anchor norm ----
// One wave (64 lanes) per row; D = 256 -> float4 per lane.
// Writes float2 {pos_sim, norm_a} per row.
__global__ void pos_sim_kernel(const float* __restrict__ anchor,
                               const float* __restrict__ pos,
                               float2* __restrict__ pn,
                               int B) {
    int wave = (blockIdx.x * blockDim.x + threadIdx.x) >> 6;
    int lane = threadIdx.x & 63;
    if (wave >= B) return;

    const float4 a = *reinterpret_cast<const float4*>(anchor + (size_t)wave * 256 + lane * 4);
    const float4 p = *reinterpret_cast<const float4*>(pos    + (size_t)wave * 256 + lane * 4);

    float dot = a.x * p.x + a.y * p.y + a.z * p.z + a.w * p.w;
    float na  = a.x * a.x + a.y * a.y + a.z * a.z + a.w * a.w;
    float nb  = p.x * p.x + p.y * p.y + p.z * p.z + p.w * p.w;

    #pragma unroll
    for (int off = 32; off > 0; off >>= 1) {
        dot += __shfl_xor(dot, off);
        na  += __shfl_xor(na,  off);
        nb  += __shfl_xor(nb,  off);
    }
    if (lane == 0) {
        float sna = sqrtf(na);
        float2 r;
        r.x = dot / fmaxf(sna * sqrtf(nb), EPS);  // pos_sim
        r.y = sna;                                 // ||anchor||
        pn[wave] = r;
    }
}

// ---------------- Kernel 2: persistent, 4x-pipelined negatives -------------
// One wave per negative per iteration; grid-stride with manual 4x unroll so
// 4 independent negatives' loads (idx, anchor gather, neg stream) are in
// flight before any reduction chain starts.
__global__ void __launch_bounds__(256) neg_kernel(
        const float* __restrict__ anchor,
        const float* __restrict__ neg,
        const int*  __restrict__ idx,
        const float2* __restrict__ pn,
        float* __restrict__ sums,
        float* __restrict__ counts,
        int N) {
    const int lane   = threadIdx.x & 63;
    const int wave0  = (blockIdx.x * blockDim.x + threadIdx.x) >> 6;
    const int stride = (gridDim.x * blockDim.x) >> 6;   // total waves

    int n = wave0;
    for (; n + 3 * stride < N; n += 4 * stride) {
        const int n0 = n, n1 = n + stride, n2 = n + 2 * stride, n3 = n + 3 * stride;

        // issue all index loads
        const int b0 = idx[n0], b1 = idx[n1], b2 = idx[n2], b3 = idx[n3];

        // issue all vector loads (8 x 16B per lane in flight)
        const float4 g0 = *reinterpret_cast<const float4*>(anchor + (size_t)b0 * 256 + lane * 4);
        const float4 g1 = *reinterpret_cast<const float4*>(anchor + (size_t)b1 * 256 + lane * 4);
        const float4 g2 = *reinterpret_cast<const float4*>(anchor + (size_t)b2 * 256 + lane * 4);
        const float4 g3 = *reinterpret_cast<const float4*>(anchor + (size_t)b3 * 256 + lane * 4);
        const float4 v0 = *reinterpret_cast<const float4*>(neg + (size_t)n0 * 256 + lane * 4);
        const float4 v1 = *reinterpret_cast<const float4*>(neg + (size_t)n1 * 256 + lane * 4);
        const float4 v2 = *reinterpret_cast<const float4*>(neg + (size_t)n2 * 256 + lane * 4);
        const float4 v3 = *reinterpret_cast<const float4*>(neg + (size_t)n3 * 256 + lane * 4);

        float d0 = g0.x*v0.x + g0.y*v0.y + g0.z*v0.z + g0.w*v0.w;
        float d1 = g1.x*v1.x + g1.y*v1.y + g1.z*v1.z + g1.w*v1.w;
        float d2 = g2.x*v2.x + g2.y*v2.y + g2.z*v2.z + g2.w*v2.w;
        float d3 = g3.x*v3.x + g3.y*v3.y + g3.z*v3.z + g3.w*v3.w;
        float q0 = v0.x*v0.x + v0.y*v0.y + v0.z*v0.z + v0.w*v0.w;
        float q1 = v1.x*v1.x + v1.y*v1.y + v1.z*v1.z + v1.w*v1.w;
        float q2 = v2.x*v2.x + v2.y*v2.y + v2.z*v2.z + v2.w*v2.w;
        float q3 = v3.x*v3.x + v3.y*v3.y + v3.z*v3.z + v3.w*v3.w;

        // 8 independent butterfly chains interleave -> shfl latency hidden
        #pragma unroll
        for (int off = 32; off > 0; off >>= 1) {
            d0 += __shfl_xor(d0, off);  d1 += __shfl_xor(d1, off);
            d2 += __shfl_xor(d2, off);  d3 += __shfl_xor(d3, off);
            q0 += __shfl_xor(q0, off);  q1 += __shfl_xor(q1, off);
            q2 += __shfl_xor(q2, off);  q3 += __shfl_xor(q3, off);
        }

        if (lane == 0) {
            const float2 p0 = pn[b0], p1 = pn[b1], p2 = pn[b2], p3 = pn[b3];
            float t0 = fmaxf(MARGIN + d0 / fmaxf(p0.y * sqrtf(q0), EPS) - p0.x, 0.0f);
            float t1 = fmaxf(MARGIN + d1 / fmaxf(p1.y * sqrtf(q1), EPS) - p1.x, 0.0f);
            float t2 = fmaxf(MARGIN + d2 / fmaxf(p2.y * sqrtf(q2), EPS) - p2.x, 0.0f);
            float t3 = fmaxf(MARGIN + d3 / fmaxf(p3.y * sqrtf(q3), EPS) - p3.x, 0.0f);
            atomicAdd(&sums[b0], t0);  atomicAdd(&counts[b0], 1.0f);
            atomicAdd(&sums[b1], t1);  atomicAdd(&counts[b1], 1.0f);
            atomicAdd(&sums[b2], t2);  atomicAdd(&counts[b2], 1.0f);
            atomicAdd(&sums[b3], t3);  atomicAdd(&counts[b3], 1.0f);
        }
    }
    // tail
    for (; n < N; n += stride) {
        const int b = idx[n];
        const float4 g = *reinterpret_cast<const float4*>(anchor + (size_t)b * 256 + lane * 4);
        const float4 v = *reinterpret_cast<const float4*>(neg + (size_t)n * 256 + lane * 4);
        float d = g.x*v.x + g.y*v.y + g.z*v.z + g.w*v.w;
        float q = v.x*v.x + v.y*v.y + v.z*v.z + v.w*v.w;
        #pragma unroll
        for (int off = 32; off > 0; off >>= 1) {
            d += __shfl_xor(d, off);
            q += __shfl_xor(q, off);
        }
        if (lane == 0) {
            const float2 p = pn[b];
            float t = fmaxf(MARGIN + d / fmaxf(p.y * sqrtf(q), EPS) - p.x, 0.0f);
            atomicAdd(&sums[b], t);
            atomicAdd(&counts[b], 1.0f);
        }
    }
}

// ---------------- Kernel 3: segment means -> scalar -------------------------
__global__ void finalize_kernel(const float* __restrict__ sums,
                                const float* __restrict__ counts,
                                float* __restrict__ out, int B) {
    float local = 0.0f;
    for (int i = threadIdx.x; i < B; i += blockDim.x) {
        float c = counts[i];
        local += (c > 0.0f) ? (sums[i] / c) : 0.0f;
    }
    #pragma unroll
    for (int off = 32; off > 0; off >>= 1)
        local += __shfl_xor(local, off);

    __shared__ float ws[8];
    int wid = threadIdx.x >> 6;
    if ((threadIdx.x & 63) == 0) ws[wid] = local;
    __syncthreads();
    if (threadIdx.x == 0) {
        float tot = 0.0f;
        int nw = blockDim.x >> 6;
        for (int w = 0; w < nw; ++w) tot += ws[w];
        out[0] = tot / (float)B;
    }
}

extern "C" void kernel_launch(void* const* d_in, const int* in_sizes, int n_in,
                              void* d_out, int out_size, void* d_ws, size_t ws_size,
                              hipStream_t stream) {
    const float* anchor = (const float*)d_in[0];
    const float* pos    = (const float*)d_in[1];
    const float* neg    = (const float*)d_in[2];
    const int*   idx    = (const int*)d_in[3];

    const int D = 256;
    int B = in_sizes[0] / D;   // 4096
    int N = in_sizes[3];       // 262144

    float2* pn     = (float2*)d_ws;            // B float2
    float*  sums   = (float*)(pn + B);         // B floats
    float*  counts = sums + B;                 // B floats

    // zero the segment accumulators (harness poisons ws with 0xAA)
    hipMemsetAsync(sums, 0, 2 * (size_t)B * sizeof(float), stream);

    // kernel 1: B waves
    {
        int threads = 256;
        int blocks = (B + 3) / 4;
        pos_sim_kernel<<<blocks, threads, 0, stream>>>(anchor, pos, pn, B);
    }

    // kernel 2: persistent grid, 8192 waves, grid-stride + 4x pipeline
    {
        int threads = 256;
        int blocks  = 2048;   // 8 blocks/CU
        neg_kernel<<<blocks, threads, 0, stream>>>(anchor, neg, idx, pn,
                                                   sums, counts, N);
    }

    // kernel 3: reduce to scalar
    finalize_kernel<<<1, 256, 0, stream>>>(sums, counts, (float*)d_out, B);
}

// Round 3
// 90.153 us; speedup vs baseline: 1.1157x; 1.0132x over previous
//
#include <hip/hip_runtime.h>
#include <math.h>

#define EPS 1e-8f
#define MARGIN 0.5f

typedef float f4 __attribute__((ext_vector_type(4)));

// ---------------- Kernel 1: per-batch-row positive cosine + anchor norm ----
// One wave (64 lanes) per row; D = 256 -> float4 per lane.
// Writes float2 {pos_sim, norm_a} per row. Also warms L2/L3 with anchor.
__global__ void pos_sim_kernel(const float* __restrict__ anchor,
                               const float* __restrict__ pos,
                               float2* __restrict__ pn,
                               int B) {
    int wave = (blockIdx.x * blockDim.x + threadIdx.x) >> 6;
    int lane = threadIdx.x & 63;
    if (wave >= B) return;

    const f4 a = *(reinterpret_cast<const f4*>(anchor + (size_t)wave * 256) + lane);
    const f4 p = *(reinterpret_cast<const f4*>(pos    + (size_t)wave * 256) + lane);

    float dot = a.x * p.x + a.y * p.y + a.z * p.z + a.w * p.w;
    float na  = a.x * a.x + a.y * a.y + a.z * a.z + a.w * a.w;
    float nb  = p.x * p.x + p.y * p.y + p.z * p.z + p.w * p.w;

    #pragma unroll
    for (int off = 32; off > 0; off >>= 1) {
        dot += __shfl_xor(dot, off);
        na  += __shfl_xor(na,  off);
        nb  += __shfl_xor(nb,  off);
    }
    if (lane == 0) {
        float sna = sqrtf(na);
        float2 r;
        r.x = dot / fmaxf(sna * sqrtf(nb), EPS);  // pos_sim
        r.y = sna;                                 // ||anchor||
        pn[wave] = r;
    }
}

// ---------------- Kernel 2: persistent, 4x-pipelined negatives -------------
// neg stream loads are NON-TEMPORAL (evict-first) so the 4 MB anchor table
// stays L2-resident for the gather. anchor loads stay temporal.
__global__ void __launch_bounds__(256) neg_kernel(
        const float* __restrict__ anchor,
        const float* __restrict__ neg,
        const int*  __restrict__ idx,
        const float2* __restrict__ pn,
        float* __restrict__ sums,
        float* __restrict__ counts,
        int N) {
    const int lane   = threadIdx.x & 63;
    const int wave0  = (blockIdx.x * blockDim.x + threadIdx.x) >> 6;
    const int stride = (gridDim.x * blockDim.x) >> 6;   // total waves

    int n = wave0;
    for (; n + 3 * stride < N; n += 4 * stride) {
        const int n0 = n, n1 = n + stride, n2 = n + 2 * stride, n3 = n + 3 * stride;

        const int b0 = idx[n0], b1 = idx[n1], b2 = idx[n2], b3 = idx[n3];

        // anchor gathers: temporal (want these to stay in L2)
        const f4 g0 = *(reinterpret_cast<const f4*>(anchor + (size_t)b0 * 256) + lane);
        const f4 g1 = *(reinterpret_cast<const f4*>(anchor + (size_t)b1 * 256) + lane);
        const f4 g2 = *(reinterpret_cast<const f4*>(anchor + (size_t)b2 * 256) + lane);
        const f4 g3 = *(reinterpret_cast<const f4*>(anchor + (size_t)b3 * 256) + lane);
        // neg stream: non-temporal (read once, don't pollute L2/L3)
        const f4 v0 = __builtin_nontemporal_load(reinterpret_cast<const f4*>(neg + (size_t)n0 * 256) + lane);
        const f4 v1 = __builtin_nontemporal_load(reinterpret_cast<const f4*>(neg + (size_t)n1 * 256) + lane);
        const f4 v2 = __builtin_nontemporal_load(reinterpret_cast<const f4*>(neg + (size_t)n2 * 256) + lane);
        const f4 v3 = __builtin_nontemporal_load(reinterpret_cast<const f4*>(neg + (size_t)n3 * 256) + lane);

        float d0 = g0.x*v0.x + g0.y*v0.y + g0.z*v0.z + g0.w*v0.w;
        float d1 = g1.x*v1.x + g1.y*v1.y + g1.z*v1.z + g1.w*v1.w;
        float d2 = g2.x*v2.x + g2.y*v2.y + g2.z*v2.z + g2.w*v2.w;
        float d3 = g3.x*v3.x + g3.y*v3.y + g3.z*v3.z + g3.w*v3.w;
        float q0 = v0.x*v0.x + v0.y*v0.y + v0.z*v0.z + v0.w*v0.w;
        float q1 = v1.x*v1.x + v1.y*v1.y + v1.z*v1.z + v1.w*v1.w;
        float q2 = v2.x*v2.x + v2.y*v2.y + v2.z*v2.z + v2.w*v2.w;
        float q3 = v3.x*v3.x + v3.y*v3.y + v3.z*v3.z + v3.w*v3.w;

        #pragma unroll
        for (int off = 32; off > 0; off >>= 1) {
            d0 += __shfl_xor(d0, off);  d1 += __shfl_xor(d1, off);
            d2 += __shfl_xor(d2, off);  d3 += __shfl_xor(d3, off);
            q0 += __shfl_xor(q0, off);  q1 += __shfl_xor(q1, off);
            q2 += __shfl_xor(q2, off);  q3 += __shfl_xor(q3, off);
        }

        if (lane == 0) {
            const float2 p0 = pn[b0], p1 = pn[b1], p2 = pn[b2], p3 = pn[b3];
            float t0 = fmaxf(MARGIN + d0 / fmaxf(p0.y * sqrtf(q0), EPS) - p0.x, 0.0f);
            float t1 = fmaxf(MARGIN + d1 / fmaxf(p1.y * sqrtf(q1), EPS) - p1.x, 0.0f);
            float t2 = fmaxf(MARGIN + d2 / fmaxf(p2.y * sqrtf(q2), EPS) - p2.x, 0.0f);
            float t3 = fmaxf(MARGIN + d3 / fmaxf(p3.y * sqrtf(q3), EPS) - p3.x, 0.0f);
            atomicAdd(&sums[b0], t0);  atomicAdd(&counts[b0], 1.0f);
            atomicAdd(&sums[b1], t1);  atomicAdd(&counts[b1], 1.0f);
            atomicAdd(&sums[b2], t2);  atomicAdd(&counts[b2], 1.0f);
            atomicAdd(&sums[b3], t3);  atomicAdd(&counts[b3], 1.0f);
        }
    }
    // tail
    for (; n < N; n += stride) {
        const int b = idx[n];
        const f4 g = *(reinterpret_cast<const f4*>(anchor + (size_t)b * 256) + lane);
        const f4 v = __builtin_nontemporal_load(reinterpret_cast<const f4*>(neg + (size_t)n * 256) + lane);
        float d = g.x*v.x + g.y*v.y + g.z*v.z + g.w*v.w;
        float q = v.x*v.x + v.y*v.y + v.z*v.z + v.w*v.w;
        #pragma unroll
        for (int off = 32; off > 0; off >>= 1) {
            d += __shfl_xor(d, off);
            q += __shfl_xor(q, off);
        }
        if (lane == 0) {
            const float2 p = pn[b];
            float t = fmaxf(MARGIN + d / fmaxf(p.y * sqrtf(q), EPS) - p.x, 0.0f);
            atomicAdd(&sums[b], t);
            atomicAdd(&counts[b], 1.0f);
        }
    }
}

// ---------------- Kernel 3: segment means -> scalar (parallel) -------------
// 16 blocks x 256 threads cover B=4096; per-wave reduce then one atomicAdd
// per wave (64 atomics total). d_out is zeroed by memset before this runs.
__global__ void finalize_kernel(const float* __restrict__ sums,
                                const float* __restrict__ counts,
                                float* __restrict__ out, int B) {
    int i = blockIdx.x * blockDim.x + threadIdx.x;
    float local = 0.0f;
    if (i < B) {
        float c = counts[i];
        local = (c > 0.0f) ? (sums[i] / c) : 0.0f;
    }
    #pragma unroll
    for (int off = 32; off > 0; off >>= 1)
        local += __shfl_xor(local, off);
    if ((threadIdx.x & 63) == 0)
        atomicAdd(out, local / (float)B);
}

extern "C" void kernel_launch(void* const* d_in, const int* in_sizes, int n_in,
                              void* d_out, int out_size, void* d_ws, size_t ws_size,
                              hipStream_t stream) {
    const float* anchor = (const float*)d_in[0];
    const float* pos    = (const float*)d_in[1];
    const float* neg    = (const float*)d_in[2];
    const int*   idx    = (const int*)d_in[3];

    const int D = 256;
    int B = in_sizes[0] / D;   // 4096
    int N = in_sizes[3];       // 262144

    float2* pn     = (float2*)d_ws;            // B float2
    float*  sums   = (float*)(pn + B);         // B floats
    float*  counts = sums + B;                 // B floats

    // zero segment accumulators and the output scalar
    hipMemsetAsync(sums, 0, 2 * (size_t)B * sizeof(float), stream);
    hipMemsetAsync(d_out, 0, sizeof(float), stream);

    // kernel 1: B waves (also warms L2/L3 with anchor)
    {
        int threads = 256;
        int blocks = (B + 3) / 4;
        pos_sim_kernel<<<blocks, threads, 0, stream>>>(anchor, pos, pn, B);
    }

    // kernel 2: persistent grid, 8192 waves, grid-stride + 4x pipeline
    {
        int threads = 256;
        int blocks  = 2048;   // 8 blocks/CU
        neg_kernel<<<blocks, threads, 0, stream>>>(anchor, neg, idx, pn,
                                                   sums, counts, N);
    }

    // kernel 3: parallel reduce to scalar
    {
        int threads = 256;
        int blocks = (B + threads - 1) / threads;  // 16
        finalize_kernel<<<blocks, threads, 0, stream>>>(sums, counts, (float*)d_out, B);
    }
}